// Round 1
// baseline (791.209 us; speedup 1.0000x reference)
//
#include <hip/hip_runtime.h>

#define BN_EPS 1e-5f

// sizes: B=16, Cin=1024, H=W=32, HW=1024, P=256, O=1024, J=18 offset channels
// ws layout (floats):
//   w2t  @ 0        : 9*256*256 = 589824   [k][c][o]
//   owt  @ 589824   : 18*9*256  = 41472    [j][kp][c]
//   bnc  @ 631296   : 3072  (s1,t1,s2,t2 @256 each; s3 @1024 off 1024; t3 @1024 off 2048)
//   h1   @ 634368   : 16*1024*256 NHWC [b][hw][c]
//   off  @ 4828672  : 16*18*1024 NCHW [b][j][hw]
//   h2   @ 5123584  : 16*1024*256 NHWC
// total 9317888 floats = 35.6 MiB

__device__ __forceinline__ float4 f4fma(float a, float4 b, float4 c) {
    return make_float4(fmaf(a, b.x, c.x), fmaf(a, b.y, c.y),
                       fmaf(a, b.z, c.z), fmaf(a, b.w, c.w));
}
__device__ __forceinline__ float f4dot(float4 a, float4 b) {
    return a.x * b.x + a.y * b.y + a.z * b.z + a.w * b.w;
}

// ---------------- prep: BN scale/shift ----------------
__global__ void __launch_bounds__(1024) k_bnprep(
    const float* g1, const float* b1, const float* m1, const float* v1,
    const float* g2, const float* b2, const float* m2, const float* v2,
    const float* g3, const float* b3, const float* m3, const float* v3,
    float* bnc) {
    int t = threadIdx.x;
    if (t < 256) {
        float s = g1[t] * rsqrtf(v1[t] + BN_EPS);
        bnc[t] = s;
        bnc[256 + t] = b1[t] - m1[t] * s;
        float s2 = g2[t] * rsqrtf(v2[t] + BN_EPS);
        bnc[512 + t] = s2;
        bnc[768 + t] = b2[t] - m2[t] * s2;
    }
    float s3 = g3[t] * rsqrtf(v3[t] + BN_EPS);
    bnc[1024 + t] = s3;
    bnc[2048 + t] = b3[t] - m3[t] * s3;
}

// ---------------- prep: transpose w2 (O,C,3,3) -> [k][c][o] ----------------
__global__ void __launch_bounds__(256) k_w2t(const float* __restrict__ w2,
                                             float* __restrict__ w2t) {
    int idx = blockIdx.x * 256 + threadIdx.x;
    if (idx >= 256 * 256 * 9) return;
    int o = idx / 2304;
    int rem = idx - o * 2304;
    int c = rem / 9;
    int k = rem - c * 9;
    w2t[(k * 256 + c) * 256 + o] = w2[idx];
}

// ---------------- prep: transpose off_w (18,C,3,3) -> [j][kp][c] ----------------
__global__ void __launch_bounds__(256) k_owt(const float* __restrict__ ow,
                                             float* __restrict__ owt) {
    int idx = blockIdx.x * 256 + threadIdx.x;
    if (idx >= 18 * 256 * 9) return;
    int j = idx / 2304;
    int rem = idx - j * 2304;
    int c = rem / 9;
    int kp = rem - c * 9;
    owt[(j * 9 + kp) * 256 + c] = ow[idx];
}

// ---------------- K1: conv1x1 (K=1024) + BN1 + ReLU -> h1 NHWC ----------------
// grid (16 hw-tiles, 4 p-tiles, 16 b), 256 thr; 64x64 tile, 4x4 microtile
__global__ void __launch_bounds__(256) k_conv1(const float* __restrict__ x,
                                               const float* __restrict__ w1,
                                               const float* __restrict__ bnc,
                                               float* __restrict__ h1) {
    __shared__ float As[16 * 68];
    __shared__ float Bs[16 * 68];
    int t = threadIdx.x;
    int hw0 = blockIdx.x * 64, p0 = blockIdx.y * 64, b = blockIdx.z;
    int tx = t & 15, ty = t >> 4;
    float acc[4][4];
#pragma unroll
    for (int i = 0; i < 4; ++i)
#pragma unroll
        for (int j = 0; j < 4; ++j) acc[i][j] = 0.f;

    const float4* x4 = (const float4*)x;
    const float4* w14 = (const float4*)w1;
    float4* As4 = (float4*)As;
    float4* Bs4 = (float4*)Bs;
    int lakk = t >> 4, lai = t & 15;     // A loader: (kk, i4)
    int lbj = t >> 2, lbk = (t & 3) * 4; // B loader: (j, kq)

    for (int c0 = 0; c0 < 1024; c0 += 16) {
        As4[lakk * 17 + lai] =
            x4[(size_t)(b * 1024 + c0 + lakk) * 256 + (hw0 >> 2) + lai];
        float4 wv = w14[(size_t)(p0 + lbj) * 256 + ((c0 + lbk) >> 2)];
        Bs[(lbk + 0) * 68 + lbj] = wv.x;
        Bs[(lbk + 1) * 68 + lbj] = wv.y;
        Bs[(lbk + 2) * 68 + lbj] = wv.z;
        Bs[(lbk + 3) * 68 + lbj] = wv.w;
        __syncthreads();
#pragma unroll
        for (int kk = 0; kk < 16; ++kk) {
            float4 a = As4[kk * 17 + tx];
            float4 bv = Bs4[kk * 17 + ty];
            const float* ap = &a.x;
            const float* bp = &bv.x;
#pragma unroll
            for (int i = 0; i < 4; ++i)
#pragma unroll
                for (int j = 0; j < 4; ++j)
                    acc[i][j] = fmaf(ap[i], bp[j], acc[i][j]);
        }
        __syncthreads();
    }
    const float4* s14 = (const float4*)(bnc);
    const float4* t14 = (const float4*)(bnc + 256);
    float4 sv = s14[(p0 >> 2) + ty];
    float4 tv = t14[(p0 >> 2) + ty];
    float4* h14 = (float4*)h1;
#pragma unroll
    for (int ii = 0; ii < 4; ++ii) {
        float4 v;
        v.x = fmaxf(fmaf(acc[ii][0], sv.x, tv.x), 0.f);
        v.y = fmaxf(fmaf(acc[ii][1], sv.y, tv.y), 0.f);
        v.z = fmaxf(fmaf(acc[ii][2], sv.z, tv.z), 0.f);
        v.w = fmaxf(fmaf(acc[ii][3], sv.w, tv.w), 0.f);
        h14[(size_t)(b * 1024 + hw0 + tx * 4 + ii) * 64 + (p0 >> 2) + ty] = v;
    }
}

// ---------------- K2: 3x3 offset conv on h1 -> off [b][j][hw] ----------------
// grid (32 y, 16 b), 256 thr. LDS tile: 3 rows with x-halo, [row*34+x+1][c(128)]
__global__ void __launch_bounds__(256) k_off(const float* __restrict__ h1,
                                             const float* __restrict__ owt,
                                             const float* __restrict__ offb,
                                             float* __restrict__ off) {
    __shared__ float ls[102 * 132];
    int t = threadIdx.x;
    int y = blockIdx.x, b = blockIdx.y;
    int x = t & 31;
    int j0 = t >> 5; // 0..7 -> handles j0, j0+8, and j0+16 (if <18)
    float acc0 = 0.f, acc1 = 0.f, acc2 = 0.f;
    const float4* h14 = (const float4*)h1;
    const float4* owt4 = (const float4*)owt;
    float4* ls4 = (float4*)ls;

    for (int ch = 0; ch < 2; ++ch) {
        __syncthreads();
        for (int u = t; u < 102 * 32; u += 256) {
            int row = u >> 5, c4 = u & 31;
            int r = row / 34;
            int xi = row - r * 34 - 1; // -1..32
            int yy = y + r - 1;
            float4 v = make_float4(0.f, 0.f, 0.f, 0.f);
            if (xi >= 0 && xi < 32 && yy >= 0 && yy < 32)
                v = h14[(size_t)(b * 1024 + yy * 32 + xi) * 64 + ch * 32 + c4];
            ls4[row * 33 + c4] = v;
        }
        __syncthreads();
#pragma unroll
        for (int kp = 0; kp < 9; ++kp) {
            int r = kp / 3, kx = kp - r * 3;
            const float4* hp = ls4 + (r * 34 + x + kx) * 33;
            const float4* wa = owt4 + (size_t)(j0 * 9 + kp) * 64 + ch * 32;
            const float4* wb = owt4 + (size_t)((j0 + 8) * 9 + kp) * 64 + ch * 32;
            int j2 = (j0 < 2) ? (j0 + 16) : 0;
            const float4* wc = owt4 + (size_t)(j2 * 9 + kp) * 64 + ch * 32;
#pragma unroll 4
            for (int c4 = 0; c4 < 32; ++c4) {
                float4 h = hp[c4];
                acc0 += f4dot(h, wa[c4]);
                acc1 += f4dot(h, wb[c4]);
                if (j0 < 2) acc2 += f4dot(h, wc[c4]);
            }
        }
    }
    size_t ob = (size_t)b * 18 * 1024 + (size_t)y * 32 + x;
    off[ob + (size_t)j0 * 1024] = acc0 + offb[j0];
    off[ob + (size_t)(j0 + 8) * 1024] = acc1 + offb[j0 + 8];
    if (j0 < 2) off[ob + (size_t)(j0 + 16) * 1024] = acc2 + offb[j0 + 16];
}

// ---------------- K3: deformable conv + BN2 + ReLU -> h2 NHWC ----------------
// grid (32 y, 16 b), 256 thr. Per k: build samp[x][c] in LDS, then FMA-GEMM.
__global__ void __launch_bounds__(256) k_deform(const float* __restrict__ h1,
                                                const float* __restrict__ off,
                                                const float* __restrict__ w2t,
                                                const float* __restrict__ bnc,
                                                float* __restrict__ h2) {
    __shared__ float samp[32 * 260]; // [x][c] pitch 260
    int t = threadIdx.x;
    int y = blockIdx.x, b = blockIdx.y;
    int bx = t >> 3, cg = t & 7;    // build: x 0..31, c-group 0..7
    int xg = t & 3, og = t >> 2;    // gemm: x = xg+4i, o = og*4..+4
    float4 acc[8];
#pragma unroll
    for (int i = 0; i < 8; ++i) acc[i] = make_float4(0.f, 0.f, 0.f, 0.f);

    const float4* h14 = (const float4*)h1;
    const float4* w2t4 = (const float4*)w2t;
    float4* samp4 = (float4*)samp;
    size_t obase = (size_t)b * 18 * 1024 + (size_t)y * 32 + bx;

    for (int k = 0; k < 9; ++k) {
        __syncthreads(); // previous GEMM done reading samp
        // ---- build bilinear-sampled tile for tap k ----
        float oy = off[obase + (size_t)(2 * k) * 1024];
        float ox = off[obase + (size_t)(2 * k + 1) * 1024];
        float py = (float)y + (float)(k / 3 - 1) + oy;
        float px = (float)bx + (float)(k % 3 - 1) + ox;
        float fy = floorf(py), fx = floorf(px);
        float wy = py - fy, wx = px - fx;
        int y0 = (int)fy, x0 = (int)fx;
        int y1 = y0 + 1, x1 = x0 + 1;
        float vy0 = (y0 >= 0 && y0 < 32) ? 1.f : 0.f;
        float vy1 = (y1 >= 0 && y1 < 32) ? 1.f : 0.f;
        float vx0 = (x0 >= 0 && x0 < 32) ? 1.f : 0.f;
        float vx1 = (x1 >= 0 && x1 < 32) ? 1.f : 0.f;
        int yc0 = min(max(y0, 0), 31), yc1 = min(max(y1, 0), 31);
        int xc0 = min(max(x0, 0), 31), xc1 = min(max(x1, 0), 31);
        float w00 = (1.f - wy) * (1.f - wx) * vy0 * vx0;
        float w01 = (1.f - wy) * wx * vy0 * vx1;
        float w10 = wy * (1.f - wx) * vy1 * vx0;
        float w11 = wy * wx * vy1 * vx1;
        const float4* p00 = h14 + ((size_t)(b * 1024 + yc0 * 32 + xc0) << 6);
        const float4* p01 = h14 + ((size_t)(b * 1024 + yc0 * 32 + xc1) << 6);
        const float4* p10 = h14 + ((size_t)(b * 1024 + yc1 * 32 + xc0) << 6);
        const float4* p11 = h14 + ((size_t)(b * 1024 + yc1 * 32 + xc1) << 6);
#pragma unroll
        for (int q = 0; q < 8; ++q) {
            int c4 = cg * 8 + q;
            float4 v = make_float4(0.f, 0.f, 0.f, 0.f);
            v = f4fma(w00, p00[c4], v);
            v = f4fma(w01, p01[c4], v);
            v = f4fma(w10, p10[c4], v);
            v = f4fma(w11, p11[c4], v);
            samp4[bx * 65 + c4] = v;
        }
        __syncthreads();
        // ---- GEMM accumulate: acc[x][o] += samp[x][c] * w2t[k][c][o] ----
        const float4* wp = w2t4 + (size_t)k * 16384 + og;
        const float* sp = samp + xg * 260;
#pragma unroll 4
        for (int c = 0; c < 256; ++c) {
            float4 w = wp[(size_t)c * 64];
#pragma unroll
            for (int i = 0; i < 8; ++i)
                acc[i] = f4fma(sp[i * 1040 + c], w, acc[i]);
        }
    }
    const float4* s24 = (const float4*)(bnc + 512);
    const float4* t24 = (const float4*)(bnc + 768);
    float4 sv = s24[og], tv = t24[og];
    float4* h24 = (float4*)h2;
#pragma unroll
    for (int i = 0; i < 8; ++i) {
        float4 v;
        v.x = fmaxf(fmaf(acc[i].x, sv.x, tv.x), 0.f);
        v.y = fmaxf(fmaf(acc[i].y, sv.y, tv.y), 0.f);
        v.z = fmaxf(fmaf(acc[i].z, sv.z, tv.z), 0.f);
        v.w = fmaxf(fmaf(acc[i].w, sv.w, tv.w), 0.f);
        h24[(size_t)(b * 1024 + y * 32 + xg + 4 * i) * 64 + og] = v;
    }
}

// ---------------- K4: conv1x1 (K=256) + BN3 + residual + ReLU -> out NCHW ----
// grid (16 hw-tiles, 16 o-tiles, 16 b), 256 thr
__global__ void __launch_bounds__(256) k_conv3(const float* __restrict__ h2,
                                               const float* __restrict__ w3,
                                               const float* __restrict__ bnc,
                                               const float* __restrict__ xin,
                                               float* __restrict__ out) {
    __shared__ float As[16 * 68];
    __shared__ float Bs[16 * 68];
    int t = threadIdx.x;
    int hw0 = blockIdx.x * 64, o0 = blockIdx.y * 64, b = blockIdx.z;
    int tx = t & 15, ty = t >> 4;
    float acc[4][4];
#pragma unroll
    for (int i = 0; i < 4; ++i)
#pragma unroll
        for (int j = 0; j < 4; ++j) acc[i][j] = 0.f;

    const float4* h24 = (const float4*)h2;
    const float4* w34 = (const float4*)w3;
    float4* As4 = (float4*)As;
    float4* Bs4 = (float4*)Bs;
    int li = t >> 2, lk = (t & 3) * 4; // loader: (row, kq)

    for (int c0 = 0; c0 < 256; c0 += 16) {
        float4 hv = h24[(size_t)(b * 1024 + hw0 + li) * 64 + ((c0 + lk) >> 2)];
        As[(lk + 0) * 68 + li] = hv.x;
        As[(lk + 1) * 68 + li] = hv.y;
        As[(lk + 2) * 68 + li] = hv.z;
        As[(lk + 3) * 68 + li] = hv.w;
        float4 wv = w34[(size_t)(o0 + li) * 64 + ((c0 + lk) >> 2)];
        Bs[(lk + 0) * 68 + li] = wv.x;
        Bs[(lk + 1) * 68 + li] = wv.y;
        Bs[(lk + 2) * 68 + li] = wv.z;
        Bs[(lk + 3) * 68 + li] = wv.w;
        __syncthreads();
#pragma unroll
        for (int kk = 0; kk < 16; ++kk) {
            float4 a = As4[kk * 17 + tx];
            float4 bv = Bs4[kk * 17 + ty];
            const float* ap = &a.x;
            const float* bp = &bv.x;
#pragma unroll
            for (int i = 0; i < 4; ++i)
#pragma unroll
                for (int j = 0; j < 4; ++j)
                    acc[i][j] = fmaf(ap[i], bp[j], acc[i][j]);
        }
        __syncthreads();
    }
    const float* s3 = bnc + 1024;
    const float* t3 = bnc + 2048;
    const float4* xin4 = (const float4*)xin;
    float4* out4 = (float4*)out;
#pragma unroll
    for (int jj = 0; jj < 4; ++jj) {
        int o = o0 + ty * 4 + jj;
        float s = s3[o], tt = t3[o];
        size_t idx = (size_t)(b * 1024 + o) * 256 + (hw0 >> 2) + tx;
        float4 r = xin4[idx];
        float4 v;
        v.x = fmaxf(fmaf(acc[0][jj], s, tt) + r.x, 0.f);
        v.y = fmaxf(fmaf(acc[1][jj], s, tt) + r.y, 0.f);
        v.z = fmaxf(fmaf(acc[2][jj], s, tt) + r.z, 0.f);
        v.w = fmaxf(fmaf(acc[3][jj], s, tt) + r.w, 0.f);
        out4[idx] = v;
    }
}

extern "C" void kernel_launch(void* const* d_in, const int* in_sizes, int n_in,
                              void* d_out, int out_size, void* d_ws, size_t ws_size,
                              hipStream_t stream) {
    const float* x = (const float*)d_in[0];
    const float* w1 = (const float*)d_in[1];
    const float* bn1g = (const float*)d_in[2];
    const float* bn1b = (const float*)d_in[3];
    const float* bn1m = (const float*)d_in[4];
    const float* bn1v = (const float*)d_in[5];
    const float* off_w = (const float*)d_in[6];
    const float* off_b = (const float*)d_in[7];
    const float* w2 = (const float*)d_in[8];
    const float* bn2g = (const float*)d_in[9];
    const float* bn2b = (const float*)d_in[10];
    const float* bn2m = (const float*)d_in[11];
    const float* bn2v = (const float*)d_in[12];
    const float* w3 = (const float*)d_in[13];
    const float* bn3g = (const float*)d_in[14];
    const float* bn3b = (const float*)d_in[15];
    const float* bn3m = (const float*)d_in[16];
    const float* bn3v = (const float*)d_in[17];
    float* out = (float*)d_out;

    float* ws = (float*)d_ws;
    float* w2t = ws;               // 589824
    float* owt = ws + 589824;      // 41472
    float* bnc = ws + 631296;      // 3072
    float* h1 = ws + 634368;       // 4194304
    float* off = ws + 4828672;     // 294912
    float* h2 = ws + 5123584;      // 4194304

    k_bnprep<<<1, 1024, 0, stream>>>(bn1g, bn1b, bn1m, bn1v, bn2g, bn2b, bn2m,
                                     bn2v, bn3g, bn3b, bn3m, bn3v, bnc);
    k_w2t<<<2304, 256, 0, stream>>>(w2, w2t);
    k_owt<<<162, 256, 0, stream>>>(off_w, owt);
    k_conv1<<<dim3(16, 4, 16), 256, 0, stream>>>(x, w1, bnc, h1);
    k_off<<<dim3(32, 16), 256, 0, stream>>>(h1, owt, off_b, off);
    k_deform<<<dim3(32, 16), 256, 0, stream>>>(h1, off, w2t, bnc, h2);
    k_conv3<<<dim3(16, 16, 16), 256, 0, stream>>>(h2, w3, bnc, x, out);
}

// Round 3
// 453.695 us; speedup vs baseline: 1.7439x; 1.7439x over previous
//
#include <hip/hip_runtime.h>

#define BN_EPS 1e-5f

typedef __bf16 bf16_t;
typedef __bf16 bf16x8 __attribute__((ext_vector_type(8)));
typedef float f32x4 __attribute__((ext_vector_type(4)));

// ws layout (bytes):
//   bnc  f32   3072 elems  @ 0
//   owt  f32   41472       @ 12288
//   off  f32   294912      @ 178176
//   xb   bf16  16777216    @ 1357824
//   w1b  bf16  262144      @ 34912256
//   w2tb bf16  589824      @ 35436544   [o][k][c]
//   w3b  bf16  262144      @ 36616192
//   h1b  bf16  4194304     @ 37140480   [b*hw][c=256]
//   h2b  bf16  4194304     @ 45529088
//   total ~51.4 MB

__device__ __forceinline__ float f4dot(float4 a, float4 b) {
    return a.x * b.x + a.y * b.y + a.z * b.z + a.w * b.w;
}

// ---------------- prep: BN scale/shift ----------------
__global__ void __launch_bounds__(1024) k_bnprep(
    const float* g1, const float* b1, const float* m1, const float* v1,
    const float* g2, const float* b2, const float* m2, const float* v2,
    const float* g3, const float* b3, const float* m3, const float* v3,
    float* bnc) {
    int t = threadIdx.x;
    if (t < 256) {
        float s = g1[t] * rsqrtf(v1[t] + BN_EPS);
        bnc[t] = s;
        bnc[256 + t] = b1[t] - m1[t] * s;
        float s2 = g2[t] * rsqrtf(v2[t] + BN_EPS);
        bnc[512 + t] = s2;
        bnc[768 + t] = b2[t] - m2[t] * s2;
    }
    float s3 = g3[t] * rsqrtf(v3[t] + BN_EPS);
    bnc[1024 + t] = s3;
    bnc[2048 + t] = b3[t] - m3[t] * s3;
}

// ---------------- prep: fp32 -> bf16 cast ----------------
__global__ void __launch_bounds__(256) k_cast(const float* __restrict__ s,
                                              bf16_t* __restrict__ d, int n4) {
    int i = blockIdx.x * 256 + threadIdx.x;
    if (i >= n4) return;
    float4 v = ((const float4*)s)[i];
    d[4 * i + 0] = (bf16_t)v.x;
    d[4 * i + 1] = (bf16_t)v.y;
    d[4 * i + 2] = (bf16_t)v.z;
    d[4 * i + 3] = (bf16_t)v.w;
}

// ---------------- prep: w2 (O,C,3,3) -> bf16 [o][k][c] ----------------
__global__ void __launch_bounds__(256) k_w2b(const float* __restrict__ w2,
                                             bf16_t* __restrict__ w2t) {
    int i = blockIdx.x * 256 + threadIdx.x; // out idx
    int o = i / 2304;
    int r = i - o * 2304;
    int kk = r >> 8;
    int c = r & 255;
    w2t[i] = (bf16_t)w2[(size_t)o * 2304 + c * 9 + kk];
}

// ---------------- prep: off_w (18,C,3,3) -> f32 [j][kp][c] ----------------
__global__ void __launch_bounds__(256) k_owt(const float* __restrict__ ow,
                                             float* __restrict__ owt) {
    int idx = blockIdx.x * 256 + threadIdx.x;
    int j = idx / 2304;
    int rem = idx - j * 2304;
    int c = rem / 9;
    int kp = rem - c * 9;
    owt[(j * 9 + kp) * 256 + c] = ow[idx];
}

// ---------------- prep: x NCHW f32 -> xb NHWC bf16 ----------------
// grid (16 hw-tiles, 16 c-tiles, 16 b); 64c x 64hw tile via LDS
__global__ void __launch_bounds__(256) k_xb(const float* __restrict__ x,
                                            bf16_t* __restrict__ xb) {
    __shared__ float ld[64 * 68];
    int t = threadIdx.x;
    int hw0 = blockIdx.x * 64, c0 = blockIdx.y * 64, b = blockIdx.z;
    int ci = t >> 2, h0 = (t & 3) * 16;
    const float* src = x + ((size_t)(b * 1024 + c0 + ci) << 10) + hw0 + h0;
#pragma unroll
    for (int i = 0; i < 4; ++i)
        *(float4*)(ld + ci * 68 + h0 + 4 * i) = *(const float4*)(src + 4 * i);
    __syncthreads();
    int r = t >> 2, cc0 = (t & 3) * 16;
    bf16x8 o0, o1;
#pragma unroll
    for (int i = 0; i < 8; ++i) o0[i] = (bf16_t)ld[(cc0 + i) * 68 + r];
#pragma unroll
    for (int i = 0; i < 8; ++i) o1[i] = (bf16_t)ld[(cc0 + 8 + i) * 68 + r];
    bf16_t* dst = xb + ((size_t)(b * 1024 + hw0 + r) << 10) + c0 + cc0;
    *(bf16x8*)dst = o0;
    *(bf16x8*)(dst + 8) = o1;
}

// ---------------- shared MFMA GEMM: C[m][n] = A[m][K] * Bt[n][K]^T --------
// BM=64 BN=128 BK=32, 256 thr = 4 waves (2x2), wave: 32x64 (2x4 frags)
// epi 0: outb[m*ldo+n] = bf16(relu(acc*sc[n]+sh[n]))
// epi 1: outf NCHW fp32: relu(acc*sc[o]+sh[o] + resid), float4 rows
__global__ void __launch_bounds__(256) k_gemm64(
    const bf16_t* __restrict__ A, const bf16_t* __restrict__ Bt, int K, int ldo,
    const float* __restrict__ sc, const float* __restrict__ sh,
    const float* __restrict__ resid, bf16_t* __restrict__ outb,
    float* __restrict__ outf, int epi) {
    __shared__ __align__(16) bf16_t As[64 * 40];
    __shared__ __align__(16) bf16_t Bs[128 * 40];
    int t = threadIdx.x;
    int lane = t & 63;
    int w = t >> 6;
    int wm = w >> 1, wn = w & 1;
    int m0 = blockIdx.x * 64, n0 = blockIdx.y * 128;

    // staging maps
    int ar = t >> 2, as_ = t & 3;
    const bf16_t* ag = A + (size_t)(m0 + ar) * K + as_ * 8;
    int aw = ar * 40 + ((as_ ^ (ar & 3)) * 8);
    int bn0 = t >> 2, bs_ = t & 3;
    const bf16_t* bg0 = Bt + (size_t)(n0 + bn0) * K + bs_ * 8;
    const bf16_t* bg1 = Bt + (size_t)(n0 + 64 + bn0) * K + bs_ * 8;
    int bw0 = bn0 * 40 + ((bs_ ^ (bn0 & 3)) * 8);
    int bw1 = (64 + bn0) * 40 + ((bs_ ^ (bn0 & 3)) * 8);

    // fragment read offsets
    int asel = lane >> 4;
    int ar0 = wm * 32 + (lane & 15);
    int aoff0 = ar0 * 40 + ((asel ^ (ar0 & 3)) * 8);
    int aoff1 = (ar0 + 16) * 40 + ((asel ^ (ar0 & 3)) * 8);
    int boff[4];
#pragma unroll
    for (int ni = 0; ni < 4; ++ni) {
        int n = wn * 64 + ni * 16 + (lane & 15);
        boff[ni] = n * 40 + ((asel ^ (n & 3)) * 8);
    }
    f32x4 acc[2][4] = {};

    for (int k0 = 0; k0 < K; k0 += 32) {
        __syncthreads();
        *(bf16x8*)(As + aw) = *(const bf16x8*)(ag + k0);
        *(bf16x8*)(Bs + bw0) = *(const bf16x8*)(bg0 + k0);
        *(bf16x8*)(Bs + bw1) = *(const bf16x8*)(bg1 + k0);
        __syncthreads();
        bf16x8 a0 = *(const bf16x8*)(As + aoff0);
        bf16x8 a1 = *(const bf16x8*)(As + aoff1);
#pragma unroll
        for (int ni = 0; ni < 4; ++ni) {
            bf16x8 bv = *(const bf16x8*)(Bs + boff[ni]);
            acc[0][ni] = __builtin_amdgcn_mfma_f32_16x16x32_bf16(a0, bv, acc[0][ni], 0, 0, 0);
            acc[1][ni] = __builtin_amdgcn_mfma_f32_16x16x32_bf16(a1, bv, acc[1][ni], 0, 0, 0);
        }
    }

    int mrb = m0 + wm * 32 + (lane >> 4) * 4;
    int ncb = n0 + wn * 64 + (lane & 15);
    if (epi == 0) {
#pragma unroll
        for (int mi = 0; mi < 2; ++mi)
#pragma unroll
            for (int ni = 0; ni < 4; ++ni) {
                int n = ncb + ni * 16;
                float s = sc[n], h = sh[n];
#pragma unroll
                for (int j = 0; j < 4; ++j) {
                    int m = mrb + mi * 16 + j;
                    float v = fmaxf(fmaf(acc[mi][ni][j], s, h), 0.f);
                    outb[(size_t)m * ldo + n] = (bf16_t)v;
                }
            }
    } else {
#pragma unroll
        for (int mi = 0; mi < 2; ++mi) {
            int m = mrb + mi * 16;
            int bb = m >> 10, hw = m & 1023;
#pragma unroll
            for (int ni = 0; ni < 4; ++ni) {
                int o = ncb + ni * 16;
                float s = sc[o], h = sh[o];
                size_t idx = (((size_t)(bb * 1024 + o)) << 10) + hw;
                float4 r = *(const float4*)(resid + idx);
                float4 v;
                v.x = fmaxf(fmaf(acc[mi][ni][0], s, h) + r.x, 0.f);
                v.y = fmaxf(fmaf(acc[mi][ni][1], s, h) + r.y, 0.f);
                v.z = fmaxf(fmaf(acc[mi][ni][2], s, h) + r.z, 0.f);
                v.w = fmaxf(fmaf(acc[mi][ni][3], s, h) + r.w, 0.f);
                *(float4*)(outf + idx) = v;
            }
        }
    }
}

// ---------------- K2: 3x3 offset conv (bf16 h1, fp32 math) ----------------
__global__ void __launch_bounds__(256) k_off(const bf16_t* __restrict__ h1,
                                             const float* __restrict__ owt,
                                             const float* __restrict__ offb,
                                             float* __restrict__ off) {
    __shared__ float ls[102 * 132];
    int t = threadIdx.x;
    int y = blockIdx.x, b = blockIdx.y;
    int x = t & 31;
    int j0 = t >> 5;
    float acc0 = 0.f, acc1 = 0.f, acc2 = 0.f;
    const float4* owt4 = (const float4*)owt;
    float4* ls4 = (float4*)ls;

    for (int ch = 0; ch < 2; ++ch) {
        __syncthreads();
        for (int u = t; u < 102 * 16; u += 256) {
            int row = u >> 4, c8 = u & 15;
            int r = row / 34;
            int xi = row - r * 34 - 1;
            int yy = y + r - 1;
            float4 lo = make_float4(0.f, 0.f, 0.f, 0.f), hi = lo;
            if (xi >= 0 && xi < 32 && yy >= 0 && yy < 32) {
                bf16x8 v = *(const bf16x8*)(h1 +
                    (((size_t)(b * 1024 + yy * 32 + xi)) << 8) + ch * 128 + c8 * 8);
                lo = make_float4((float)v[0], (float)v[1], (float)v[2], (float)v[3]);
                hi = make_float4((float)v[4], (float)v[5], (float)v[6], (float)v[7]);
            }
            ls4[row * 33 + c8 * 2] = lo;
            ls4[row * 33 + c8 * 2 + 1] = hi;
        }
        __syncthreads();
#pragma unroll
        for (int kp = 0; kp < 9; ++kp) {
            int r = kp / 3, kx = kp - r * 3;
            const float4* hp = ls4 + (r * 34 + x + kx) * 33;
            const float4* wa = owt4 + (size_t)(j0 * 9 + kp) * 64 + ch * 32;
            const float4* wb = owt4 + (size_t)((j0 + 8) * 9 + kp) * 64 + ch * 32;
            int j2 = (j0 < 2) ? (j0 + 16) : 0;
            const float4* wc = owt4 + (size_t)(j2 * 9 + kp) * 64 + ch * 32;
#pragma unroll 4
            for (int c4 = 0; c4 < 32; ++c4) {
                float4 h = hp[c4];
                acc0 += f4dot(h, wa[c4]);
                acc1 += f4dot(h, wb[c4]);
                if (j0 < 2) acc2 += f4dot(h, wc[c4]);
            }
        }
    }
    size_t ob = (size_t)b * 18 * 1024 + (size_t)y * 32 + x;
    off[ob + (size_t)j0 * 1024] = acc0 + offb[j0];
    off[ob + (size_t)(j0 + 8) * 1024] = acc1 + offb[j0 + 8];
    if (j0 < 2) off[ob + (size_t)(j0 + 16) * 1024] = acc2 + offb[j0 + 16];
}

// ---------------- K3: deformable conv, MFMA ----------------
// grid (32 y, 16 b), 256 thr = 4 waves. Per tap k: build samp[32][256] bf16
// in LDS, then 8 K-steps of 32: stage Bs[256][32] from w2tb, 8 MFMA/wave.
__global__ void __launch_bounds__(256) k_deform(const bf16_t* __restrict__ h1,
                                                const float* __restrict__ off,
                                                const bf16_t* __restrict__ w2t,
                                                const float* __restrict__ bnc,
                                                bf16_t* __restrict__ h2) {
    __shared__ __align__(16) bf16_t As[32 * 264];
    __shared__ __align__(16) bf16_t Bs[256 * 40];
    int t = threadIdx.x;
    int lane = t & 63;
    int wn = t >> 6;
    int y = blockIdx.x, b = blockIdx.y;
    int sx = t >> 3, scg = t & 7;
    int bn0 = t >> 2, bs_ = t & 3;
    int asel = lane >> 4;
    int ar0 = lane & 15;
    int boff[4];
#pragma unroll
    for (int ni = 0; ni < 4; ++ni) {
        int n = wn * 64 + ni * 16 + (lane & 15);
        boff[ni] = n * 40 + ((asel ^ (n & 3)) * 8);
    }
    f32x4 acc[2][4] = {};
    size_t obase = (size_t)b * 18432 + (size_t)y * 32 + sx;
    size_t h1row = (size_t)b * 1024;

    for (int k = 0; k < 9; ++k) {
        __syncthreads();
        // ---- build bilinear-sampled tile (bf16) ----
        float oy = off[obase + (size_t)(2 * k) * 1024];
        float ox = off[obase + (size_t)(2 * k + 1) * 1024];
        float py = (float)y + (float)(k / 3 - 1) + oy;
        float px = (float)sx + (float)(k % 3 - 1) + ox;
        float fy = floorf(py), fx = floorf(px);
        float wy = py - fy, wx = px - fx;
        int y0 = (int)fy, x0 = (int)fx;
        int y1 = y0 + 1, x1 = x0 + 1;
        float vy0 = (y0 >= 0 && y0 < 32) ? 1.f : 0.f;
        float vy1 = (y1 >= 0 && y1 < 32) ? 1.f : 0.f;
        float vx0 = (x0 >= 0 && x0 < 32) ? 1.f : 0.f;
        float vx1 = (x1 >= 0 && x1 < 32) ? 1.f : 0.f;
        int yc0 = min(max(y0, 0), 31), yc1 = min(max(y1, 0), 31);
        int xc0 = min(max(x0, 0), 31), xc1 = min(max(x1, 0), 31);
        float w00 = (1.f - wy) * (1.f - wx) * vy0 * vx0;
        float w01 = (1.f - wy) * wx * vy0 * vx1;
        float w10 = wy * (1.f - wx) * vy1 * vx0;
        float w11 = wy * wx * vy1 * vx1;
        const bf16_t* p00 = h1 + ((h1row + yc0 * 32 + xc0) << 8);
        const bf16_t* p01 = h1 + ((h1row + yc0 * 32 + xc1) << 8);
        const bf16_t* p10 = h1 + ((h1row + yc1 * 32 + xc0) << 8);
        const bf16_t* p11 = h1 + ((h1row + yc1 * 32 + xc1) << 8);
#pragma unroll
        for (int q = 0; q < 4; ++q) {
            int c = scg * 32 + q * 8;
            bf16x8 v00 = *(const bf16x8*)(p00 + c);
            bf16x8 v01 = *(const bf16x8*)(p01 + c);
            bf16x8 v10 = *(const bf16x8*)(p10 + c);
            bf16x8 v11 = *(const bf16x8*)(p11 + c);
            bf16x8 r;
#pragma unroll
            for (int e = 0; e < 8; ++e) {
                float f = w00 * (float)v00[e] + w01 * (float)v01[e] +
                          w10 * (float)v10[e] + w11 * (float)v11[e];
                r[e] = (bf16_t)f;
            }
            int slot = scg * 4 + q;
            int slotx = (slot & ~3) | ((slot & 3) ^ (sx & 3));
            *(bf16x8*)(As + sx * 264 + slotx * 8) = r;
        }
        // ---- GEMM over c (K=256 per tap) ----
        for (int c0 = 0; c0 < 256; c0 += 32) {
            __syncthreads();
            const bf16_t* wg = w2t + (size_t)k * 256 + c0 + bs_ * 8;
#pragma unroll
            for (int j = 0; j < 4; ++j) {
                int n = j * 64 + bn0;
                *(bf16x8*)(Bs + n * 40 + ((bs_ ^ (n & 3)) * 8)) =
                    *(const bf16x8*)(wg + (size_t)n * 2304);
            }
            __syncthreads();
            int sbase = c0 >> 3;
            bf16x8 a0 = *(const bf16x8*)(As + ar0 * 264 + (sbase + (asel ^ (ar0 & 3))) * 8);
            bf16x8 a1 = *(const bf16x8*)(As + (ar0 + 16) * 264 + (sbase + (asel ^ (ar0 & 3))) * 8);
#pragma unroll
            for (int ni = 0; ni < 4; ++ni) {
                bf16x8 bv = *(const bf16x8*)(Bs + boff[ni]);
                acc[0][ni] = __builtin_amdgcn_mfma_f32_16x16x32_bf16(a0, bv, acc[0][ni], 0, 0, 0);
                acc[1][ni] = __builtin_amdgcn_mfma_f32_16x16x32_bf16(a1, bv, acc[1][ni], 0, 0, 0);
            }
        }
    }
    // epilogue: BN2 + ReLU -> h2 bf16
    int mrb = (lane >> 4) * 4;
    int ncb = wn * 64 + (lane & 15);
#pragma unroll
    for (int mi = 0; mi < 2; ++mi)
#pragma unroll
        for (int ni = 0; ni < 4; ++ni) {
            int n = ncb + ni * 16;
            float s = bnc[512 + n], h = bnc[768 + n];
#pragma unroll
            for (int j = 0; j < 4; ++j) {
                int row = mrb + mi * 16 + j;
                float v = fmaxf(fmaf(acc[mi][ni][j], s, h), 0.f);
                h2[(((size_t)(b * 1024 + y * 32 + row)) << 8) + n] = (bf16_t)v;
            }
        }
}

extern "C" void kernel_launch(void* const* d_in, const int* in_sizes, int n_in,
                              void* d_out, int out_size, void* d_ws, size_t ws_size,
                              hipStream_t stream) {
    const float* x = (const float*)d_in[0];
    const float* w1 = (const float*)d_in[1];
    const float* bn1g = (const float*)d_in[2];
    const float* bn1b = (const float*)d_in[3];
    const float* bn1m = (const float*)d_in[4];
    const float* bn1v = (const float*)d_in[5];
    const float* off_w = (const float*)d_in[6];
    const float* off_b = (const float*)d_in[7];
    const float* w2 = (const float*)d_in[8];
    const float* bn2g = (const float*)d_in[9];
    const float* bn2b = (const float*)d_in[10];
    const float* bn2m = (const float*)d_in[11];
    const float* bn2v = (const float*)d_in[12];
    const float* w3 = (const float*)d_in[13];
    const float* bn3g = (const float*)d_in[14];
    const float* bn3b = (const float*)d_in[15];
    const float* bn3m = (const float*)d_in[16];
    const float* bn3v = (const float*)d_in[17];
    float* out = (float*)d_out;

    char* ws = (char*)d_ws;
    float* bnc = (float*)(ws + 0);
    float* owt = (float*)(ws + 12288);
    float* off = (float*)(ws + 178176);
    bf16_t* xb = (bf16_t*)(ws + 1357824);
    bf16_t* w1b = (bf16_t*)(ws + 34912256);
    bf16_t* w2tb = (bf16_t*)(ws + 35436544);
    bf16_t* w3b = (bf16_t*)(ws + 36616192);
    bf16_t* h1b = (bf16_t*)(ws + 37140480);
    bf16_t* h2b = (bf16_t*)(ws + 45529088);

    k_bnprep<<<1, 1024, 0, stream>>>(bn1g, bn1b, bn1m, bn1v, bn2g, bn2b, bn2m,
                                     bn2v, bn3g, bn3b, bn3m, bn3v, bnc);
    k_cast<<<256, 256, 0, stream>>>(w1, w1b, 65536);
    k_cast<<<256, 256, 0, stream>>>(w3, w3b, 65536);
    k_w2b<<<2304, 256, 0, stream>>>(w2, w2tb);
    k_owt<<<162, 256, 0, stream>>>(off_w, owt);
    k_xb<<<dim3(16, 16, 16), 256, 0, stream>>>(x, xb);
    // conv1: M=16384 N=256 K=1024
    k_gemm64<<<dim3(256, 2), 256, 0, stream>>>(xb, w1b, 1024, 256, bnc,
                                               bnc + 256, nullptr, h1b, nullptr, 0);
    k_off<<<dim3(32, 16), 256, 0, stream>>>(h1b, owt, off_b, off);
    k_deform<<<dim3(32, 16), 256, 0, stream>>>(h1b, off, w2tb, bnc, h2b);
    // conv3: M=16384 N=1024 K=256, residual + BN3 + ReLU -> out NCHW f32
    k_gemm64<<<dim3(256, 8), 256, 0, stream>>>(h2b, w3b, 256, 1024, bnc + 1024,
                                               bnc + 2048, x, nullptr, out, 1);
}

// Round 4
// 357.390 us; speedup vs baseline: 2.2139x; 1.2695x over previous
//
#include <hip/hip_runtime.h>

#define BN_EPS 1e-5f

typedef __bf16 bf16_t;
typedef __bf16 bf16x8 __attribute__((ext_vector_type(8)));
typedef float f32x4 __attribute__((ext_vector_type(4)));

// ws layout (bytes):
//   bnc   f32   3072 elems  @ 0
//   owtb  bf16  73728       @ 12288    [j pad32][kp 9][c 256]
//   off   f32   294912      @ 178176
//   xb    bf16  16777216    @ 1357824
//   w1b   bf16  262144      @ 34912256
//   w2tb  bf16  589824      @ 35436544   [o][k][c]
//   w3b   bf16  262144      @ 36616192
//   h1b   bf16  4194304     @ 37140480   [b*hw][c=256]
//   h2b   bf16  4194304     @ 45529088
//   total ~51.4 MB

// ---------------- prep: BN scale/shift ----------------
__global__ void __launch_bounds__(1024) k_bnprep(
    const float* g1, const float* b1, const float* m1, const float* v1,
    const float* g2, const float* b2, const float* m2, const float* v2,
    const float* g3, const float* b3, const float* m3, const float* v3,
    float* bnc) {
    int t = threadIdx.x;
    if (t < 256) {
        float s = g1[t] * rsqrtf(v1[t] + BN_EPS);
        bnc[t] = s;
        bnc[256 + t] = b1[t] - m1[t] * s;
        float s2 = g2[t] * rsqrtf(v2[t] + BN_EPS);
        bnc[512 + t] = s2;
        bnc[768 + t] = b2[t] - m2[t] * s2;
    }
    float s3 = g3[t] * rsqrtf(v3[t] + BN_EPS);
    bnc[1024 + t] = s3;
    bnc[2048 + t] = b3[t] - m3[t] * s3;
}

// ---------------- prep: fp32 -> bf16 cast ----------------
__global__ void __launch_bounds__(256) k_cast(const float* __restrict__ s,
                                              bf16_t* __restrict__ d, int n4) {
    int i = blockIdx.x * 256 + threadIdx.x;
    if (i >= n4) return;
    float4 v = ((const float4*)s)[i];
    d[4 * i + 0] = (bf16_t)v.x;
    d[4 * i + 1] = (bf16_t)v.y;
    d[4 * i + 2] = (bf16_t)v.z;
    d[4 * i + 3] = (bf16_t)v.w;
}

// ---------------- prep: w2 (O,C,3,3) -> bf16 [o][k][c] ----------------
__global__ void __launch_bounds__(256) k_w2b(const float* __restrict__ w2,
                                             bf16_t* __restrict__ w2t) {
    int i = blockIdx.x * 256 + threadIdx.x; // out idx
    int o = i / 2304;
    int r = i - o * 2304;
    int kk = r >> 8;
    int c = r & 255;
    w2t[i] = (bf16_t)w2[(size_t)o * 2304 + c * 9 + kk];
}

// ---------------- prep: off_w (18,C,3,3) -> bf16 [j pad32][kp][c], 0-pad ----
__global__ void __launch_bounds__(256) k_owtb(const float* __restrict__ ow,
                                              bf16_t* __restrict__ owtb) {
    int idx = blockIdx.x * 256 + threadIdx.x; // 32*9*256 = 73728
    if (idx >= 73728) return;
    int j = idx / 2304;
    int rem = idx - j * 2304;
    int kp = rem >> 8;
    int c = rem & 255;
    float v = (j < 18) ? ow[(j * 256 + c) * 9 + kp] : 0.f;
    owtb[idx] = (bf16_t)v;
}

// ---------------- prep: x NCHW f32 -> xb NHWC bf16 ----------------
// grid (16 hw-tiles, 16 c-tiles, 16 b); 64c x 64hw tile via LDS
__global__ void __launch_bounds__(256) k_xb(const float* __restrict__ x,
                                            bf16_t* __restrict__ xb) {
    __shared__ float ld[64 * 68];
    int t = threadIdx.x;
    int hw0 = blockIdx.x * 64, c0 = blockIdx.y * 64, b = blockIdx.z;
    int ci = t >> 2, h0 = (t & 3) * 16;
    const float* src = x + ((size_t)(b * 1024 + c0 + ci) << 10) + hw0 + h0;
#pragma unroll
    for (int i = 0; i < 4; ++i)
        *(float4*)(ld + ci * 68 + h0 + 4 * i) = *(const float4*)(src + 4 * i);
    __syncthreads();
    int r = t >> 2, cc0 = (t & 3) * 16;
    bf16x8 o0, o1;
#pragma unroll
    for (int i = 0; i < 8; ++i) o0[i] = (bf16_t)ld[(cc0 + i) * 68 + r];
#pragma unroll
    for (int i = 0; i < 8; ++i) o1[i] = (bf16_t)ld[(cc0 + 8 + i) * 68 + r];
    bf16_t* dst = xb + ((size_t)(b * 1024 + hw0 + r) << 10) + c0 + cc0;
    *(bf16x8*)dst = o0;
    *(bf16x8*)(dst + 8) = o1;
}

// ---------------- shared MFMA GEMM: C[m][n] = A[m][K] * Bt[n][K]^T --------
// BM=64 BN=128 BK=32, 256 thr = 4 waves (2x2), wave: 32x64 (2x4 frags)
// epi 0: outb[m*ldo+n] = bf16(relu(acc*sc[n]+sh[n]))
// epi 1: outf NCHW fp32: relu(acc*sc[o]+sh[o] + resid), float4 rows
__global__ void __launch_bounds__(256) k_gemm64(
    const bf16_t* __restrict__ A, const bf16_t* __restrict__ Bt, int K, int ldo,
    const float* __restrict__ sc, const float* __restrict__ sh,
    const float* __restrict__ resid, bf16_t* __restrict__ outb,
    float* __restrict__ outf, int epi) {
    __shared__ __align__(16) bf16_t As[64 * 40];
    __shared__ __align__(16) bf16_t Bs[128 * 40];
    int t = threadIdx.x;
    int lane = t & 63;
    int w = t >> 6;
    int wm = w >> 1, wn = w & 1;
    int m0 = blockIdx.x * 64, n0 = blockIdx.y * 128;

    // staging maps
    int ar = t >> 2, as_ = t & 3;
    const bf16_t* ag = A + (size_t)(m0 + ar) * K + as_ * 8;
    int aw = ar * 40 + ((as_ ^ (ar & 3)) * 8);
    int bn0 = t >> 2, bs_ = t & 3;
    const bf16_t* bg0 = Bt + (size_t)(n0 + bn0) * K + bs_ * 8;
    const bf16_t* bg1 = Bt + (size_t)(n0 + 64 + bn0) * K + bs_ * 8;
    int bw0 = bn0 * 40 + ((bs_ ^ (bn0 & 3)) * 8);
    int bw1 = (64 + bn0) * 40 + ((bs_ ^ (bn0 & 3)) * 8);

    // fragment read offsets
    int asel = lane >> 4;
    int ar0 = wm * 32 + (lane & 15);
    int aoff0 = ar0 * 40 + ((asel ^ (ar0 & 3)) * 8);
    int aoff1 = (ar0 + 16) * 40 + ((asel ^ (ar0 & 3)) * 8);
    int boff[4];
#pragma unroll
    for (int ni = 0; ni < 4; ++ni) {
        int n = wn * 64 + ni * 16 + (lane & 15);
        boff[ni] = n * 40 + ((asel ^ (n & 3)) * 8);
    }
    f32x4 acc[2][4] = {};

    for (int k0 = 0; k0 < K; k0 += 32) {
        __syncthreads();
        *(bf16x8*)(As + aw) = *(const bf16x8*)(ag + k0);
        *(bf16x8*)(Bs + bw0) = *(const bf16x8*)(bg0 + k0);
        *(bf16x8*)(Bs + bw1) = *(const bf16x8*)(bg1 + k0);
        __syncthreads();
        bf16x8 a0 = *(const bf16x8*)(As + aoff0);
        bf16x8 a1 = *(const bf16x8*)(As + aoff1);
#pragma unroll
        for (int ni = 0; ni < 4; ++ni) {
            bf16x8 bv = *(const bf16x8*)(Bs + boff[ni]);
            acc[0][ni] = __builtin_amdgcn_mfma_f32_16x16x32_bf16(a0, bv, acc[0][ni], 0, 0, 0);
            acc[1][ni] = __builtin_amdgcn_mfma_f32_16x16x32_bf16(a1, bv, acc[1][ni], 0, 0, 0);
        }
    }

    int mrb = m0 + wm * 32 + (lane >> 4) * 4;
    int ncb = n0 + wn * 64 + (lane & 15);
    if (epi == 0) {
#pragma unroll
        for (int mi = 0; mi < 2; ++mi)
#pragma unroll
            for (int ni = 0; ni < 4; ++ni) {
                int n = ncb + ni * 16;
                float s = sc[n], h = sh[n];
#pragma unroll
                for (int j = 0; j < 4; ++j) {
                    int m = mrb + mi * 16 + j;
                    float v = fmaxf(fmaf(acc[mi][ni][j], s, h), 0.f);
                    outb[(size_t)m * ldo + n] = (bf16_t)v;
                }
            }
    } else {
#pragma unroll
        for (int mi = 0; mi < 2; ++mi) {
            int m = mrb + mi * 16;
            int bb = m >> 10, hw = m & 1023;
#pragma unroll
            for (int ni = 0; ni < 4; ++ni) {
                int o = ncb + ni * 16;
                float s = sc[o], h = sh[o];
                size_t idx = (((size_t)(bb * 1024 + o)) << 10) + hw;
                float4 r = *(const float4*)(resid + idx);
                float4 v;
                v.x = fmaxf(fmaf(acc[mi][ni][0], s, h) + r.x, 0.f);
                v.y = fmaxf(fmaf(acc[mi][ni][1], s, h) + r.y, 0.f);
                v.z = fmaxf(fmaf(acc[mi][ni][2], s, h) + r.z, 0.f);
                v.w = fmaxf(fmaf(acc[mi][ni][3], s, h) + r.w, 0.f);
                *(float4*)(outf + idx) = v;
            }
        }
    }
}

// ---------------- K2: 3x3 offset conv, MFMA, no LDS ----------------
// grid (32 y, 16 b), 256 thr = 4 waves; wave w -> (mi = x-half, ni = j-half)
// M=32 (x), N=32 (j, 18 real), K=2304 (9 taps x 256 c). A frags read direct
// from h1 (L2-hot) with boundary zero-masking; B frags from zero-padded owtb.
__global__ void __launch_bounds__(256) k_off(const bf16_t* __restrict__ h1,
                                             const bf16_t* __restrict__ owtb,
                                             const float* __restrict__ offb,
                                             float* __restrict__ off) {
    int t = threadIdx.x;
    int lane = t & 63;
    int w = t >> 6;
    int mi = w >> 1, ni = w & 1;
    int y = blockIdx.x, b = blockIdx.y;
    int x = (lane & 15) + mi * 16;
    int ksel = lane >> 4;
    int j = (lane & 15) + ni * 16;
    f32x4 acc = {};
    const bf16_t* h1base = h1 + ((size_t)b << 18);
    const bf16_t* brow = owtb + (size_t)j * 2304 + ksel * 8;

    for (int kp = 0; kp < 9; ++kp) {
        int yy = y + kp / 3 - 1;
        int xx = x + kp % 3 - 1;
        bool vy = (yy >= 0) && (yy < 32);
        bool vx = (xx >= 0) && (xx < 32);
        const bf16_t* arow = h1base + (((size_t)(yy * 32 + xx)) << 8) + ksel * 8;
        const bf16_t* bp = brow + kp * 256;
#pragma unroll
        for (int s = 0; s < 8; ++s) {
            bf16x8 av = {};
            if (vy && vx) av = *(const bf16x8*)(arow + s * 32);
            bf16x8 bv = *(const bf16x8*)(bp + s * 32);
            acc = __builtin_amdgcn_mfma_f32_16x16x32_bf16(av, bv, acc, 0, 0, 0);
        }
    }
    if (j < 18) {
        float bias = offb[j];
        size_t ob = (size_t)b * 18432 + (size_t)j * 1024 + y * 32 + mi * 16;
#pragma unroll
        for (int r = 0; r < 4; ++r) {
            off[ob + ksel * 4 + r] = acc[r] + bias;
        }
    }
}

// ---------------- K3: deformable conv, MFMA ----------------
// grid (32 y, 16 b), 256 thr = 4 waves. Per tap k: build samp[32][256] bf16
// in LDS, then 8 K-steps of 32: stage Bs[256][32] from w2tb, 8 MFMA/wave.
__global__ void __launch_bounds__(256) k_deform(const bf16_t* __restrict__ h1,
                                                const float* __restrict__ off,
                                                const bf16_t* __restrict__ w2t,
                                                const float* __restrict__ bnc,
                                                bf16_t* __restrict__ h2) {
    __shared__ __align__(16) bf16_t As[32 * 264];
    __shared__ __align__(16) bf16_t Bs[256 * 40];
    int t = threadIdx.x;
    int lane = t & 63;
    int wn = t >> 6;
    int y = blockIdx.x, b = blockIdx.y;
    int sx = t >> 3, scg = t & 7;
    int bn0 = t >> 2, bs_ = t & 3;
    int asel = lane >> 4;
    int ar0 = lane & 15;
    int boff[4];
#pragma unroll
    for (int ni = 0; ni < 4; ++ni) {
        int n = wn * 64 + ni * 16 + (lane & 15);
        boff[ni] = n * 40 + ((asel ^ (n & 3)) * 8);
    }
    f32x4 acc[2][4] = {};
    size_t obase = (size_t)b * 18432 + (size_t)y * 32 + sx;
    size_t h1row = (size_t)b * 1024;

    for (int k = 0; k < 9; ++k) {
        __syncthreads();
        // ---- build bilinear-sampled tile (bf16) ----
        float oy = off[obase + (size_t)(2 * k) * 1024];
        float ox = off[obase + (size_t)(2 * k + 1) * 1024];
        float py = (float)y + (float)(k / 3 - 1) + oy;
        float px = (float)sx + (float)(k % 3 - 1) + ox;
        float fy = floorf(py), fx = floorf(px);
        float wy = py - fy, wx = px - fx;
        int y0 = (int)fy, x0 = (int)fx;
        int y1 = y0 + 1, x1 = x0 + 1;
        float vy0 = (y0 >= 0 && y0 < 32) ? 1.f : 0.f;
        float vy1 = (y1 >= 0 && y1 < 32) ? 1.f : 0.f;
        float vx0 = (x0 >= 0 && x0 < 32) ? 1.f : 0.f;
        float vx1 = (x1 >= 0 && x1 < 32) ? 1.f : 0.f;
        int yc0 = min(max(y0, 0), 31), yc1 = min(max(y1, 0), 31);
        int xc0 = min(max(x0, 0), 31), xc1 = min(max(x1, 0), 31);
        float w00 = (1.f - wy) * (1.f - wx) * vy0 * vx0;
        float w01 = (1.f - wy) * wx * vy0 * vx1;
        float w10 = wy * (1.f - wx) * vy1 * vx0;
        float w11 = wy * wx * vy1 * vx1;
        const bf16_t* p00 = h1 + ((h1row + yc0 * 32 + xc0) << 8);
        const bf16_t* p01 = h1 + ((h1row + yc0 * 32 + xc1) << 8);
        const bf16_t* p10 = h1 + ((h1row + yc1 * 32 + xc0) << 8);
        const bf16_t* p11 = h1 + ((h1row + yc1 * 32 + xc1) << 8);
#pragma unroll
        for (int q = 0; q < 4; ++q) {
            int c = scg * 32 + q * 8;
            bf16x8 v00 = *(const bf16x8*)(p00 + c);
            bf16x8 v01 = *(const bf16x8*)(p01 + c);
            bf16x8 v10 = *(const bf16x8*)(p10 + c);
            bf16x8 v11 = *(const bf16x8*)(p11 + c);
            bf16x8 r;
#pragma unroll
            for (int e = 0; e < 8; ++e) {
                float f = w00 * (float)v00[e] + w01 * (float)v01[e] +
                          w10 * (float)v10[e] + w11 * (float)v11[e];
                r[e] = (bf16_t)f;
            }
            int slot = scg * 4 + q;
            int slotx = (slot & ~3) | ((slot & 3) ^ (sx & 3));
            *(bf16x8*)(As + sx * 264 + slotx * 8) = r;
        }
        // ---- GEMM over c (K=256 per tap) ----
        for (int c0 = 0; c0 < 256; c0 += 32) {
            __syncthreads();
            const bf16_t* wg = w2t + (size_t)k * 256 + c0 + bs_ * 8;
#pragma unroll
            for (int j = 0; j < 4; ++j) {
                int n = j * 64 + bn0;
                *(bf16x8*)(Bs + n * 40 + ((bs_ ^ (n & 3)) * 8)) =
                    *(const bf16x8*)(wg + (size_t)n * 2304);
            }
            __syncthreads();
            int sbase = c0 >> 3;
            bf16x8 a0 = *(const bf16x8*)(As + ar0 * 264 + (sbase + (asel ^ (ar0 & 3))) * 8);
            bf16x8 a1 = *(const bf16x8*)(As + (ar0 + 16) * 264 + (sbase + (asel ^ (ar0 & 3))) * 8);
#pragma unroll
            for (int ni = 0; ni < 4; ++ni) {
                bf16x8 bv = *(const bf16x8*)(Bs + boff[ni]);
                acc[0][ni] = __builtin_amdgcn_mfma_f32_16x16x32_bf16(a0, bv, acc[0][ni], 0, 0, 0);
                acc[1][ni] = __builtin_amdgcn_mfma_f32_16x16x32_bf16(a1, bv, acc[1][ni], 0, 0, 0);
            }
        }
    }
    // epilogue: BN2 + ReLU -> h2 bf16
    int mrb = (lane >> 4) * 4;
    int ncb = wn * 64 + (lane & 15);
#pragma unroll
    for (int mi = 0; mi < 2; ++mi)
#pragma unroll
        for (int ni = 0; ni < 4; ++ni) {
            int n = ncb + ni * 16;
            float s = bnc[512 + n], h = bnc[768 + n];
#pragma unroll
            for (int j = 0; j < 4; ++j) {
                int row = mrb + mi * 16 + j;
                float v = fmaxf(fmaf(acc[mi][ni][j], s, h), 0.f);
                h2[(((size_t)(b * 1024 + y * 32 + row)) << 8) + n] = (bf16_t)v;
            }
        }
}

extern "C" void kernel_launch(void* const* d_in, const int* in_sizes, int n_in,
                              void* d_out, int out_size, void* d_ws, size_t ws_size,
                              hipStream_t stream) {
    const float* x = (const float*)d_in[0];
    const float* w1 = (const float*)d_in[1];
    const float* bn1g = (const float*)d_in[2];
    const float* bn1b = (const float*)d_in[3];
    const float* bn1m = (const float*)d_in[4];
    const float* bn1v = (const float*)d_in[5];
    const float* off_w = (const float*)d_in[6];
    const float* off_b = (const float*)d_in[7];
    const float* w2 = (const float*)d_in[8];
    const float* bn2g = (const float*)d_in[9];
    const float* bn2b = (const float*)d_in[10];
    const float* bn2m = (const float*)d_in[11];
    const float* bn2v = (const float*)d_in[12];
    const float* w3 = (const float*)d_in[13];
    const float* bn3g = (const float*)d_in[14];
    const float* bn3b = (const float*)d_in[15];
    const float* bn3m = (const float*)d_in[16];
    const float* bn3v = (const float*)d_in[17];
    float* out = (float*)d_out;

    char* ws = (char*)d_ws;
    float* bnc = (float*)(ws + 0);
    bf16_t* owtb = (bf16_t*)(ws + 12288);
    float* off = (float*)(ws + 178176);
    bf16_t* xb = (bf16_t*)(ws + 1357824);
    bf16_t* w1b = (bf16_t*)(ws + 34912256);
    bf16_t* w2tb = (bf16_t*)(ws + 35436544);
    bf16_t* w3b = (bf16_t*)(ws + 36616192);
    bf16_t* h1b = (bf16_t*)(ws + 37140480);
    bf16_t* h2b = (bf16_t*)(ws + 45529088);

    k_bnprep<<<1, 1024, 0, stream>>>(bn1g, bn1b, bn1m, bn1v, bn2g, bn2b, bn2m,
                                     bn2v, bn3g, bn3b, bn3m, bn3v, bnc);
    k_cast<<<256, 256, 0, stream>>>(w1, w1b, 65536);
    k_cast<<<256, 256, 0, stream>>>(w3, w3b, 65536);
    k_w2b<<<2304, 256, 0, stream>>>(w2, w2tb);
    k_owtb<<<288, 256, 0, stream>>>(off_w, owtb);
    k_xb<<<dim3(16, 16, 16), 256, 0, stream>>>(x, xb);
    // conv1: M=16384 N=256 K=1024
    k_gemm64<<<dim3(256, 2), 256, 0, stream>>>(xb, w1b, 1024, 256, bnc,
                                               bnc + 256, nullptr, h1b, nullptr, 0);
    k_off<<<dim3(32, 16), 256, 0, stream>>>(h1b, owtb, off_b, off);
    k_deform<<<dim3(32, 16), 256, 0, stream>>>(h1b, off, w2tb, bnc, h2b);
    // conv3: M=16384 N=1024 K=256, residual + BN3 + ReLU -> out NCHW f32
    k_gemm64<<<dim3(256, 8), 256, 0, stream>>>(h2b, w3b, 256, 1024, bnc + 1024,
                                               bnc + 2048, x, nullptr, out, 1);
}

// Round 5
// 352.872 us; speedup vs baseline: 2.2422x; 1.0128x over previous
//
#include <hip/hip_runtime.h>

#define BN_EPS 1e-5f

typedef __bf16 bf16_t;
typedef __bf16 bf16x8 __attribute__((ext_vector_type(8)));
typedef float f32x4 __attribute__((ext_vector_type(4)));

// ws layout (bytes):
//   bnc   f32   3072 elems  @ 0
//   owtb  bf16  73728       @ 12288    [j pad32][kp 9][c 256]
//   off   f32   294912      @ 178176
//   xb    bf16  16777216    @ 1357824
//   w1b   bf16  262144      @ 34912256
//   w2tb  bf16  589824      @ 35436544   [o][k][c]
//   w3b   bf16  262144      @ 36616192
//   h1b   bf16  4194304     @ 37140480   [b*hw][c=256]
//   h2b   bf16  4194304     @ 45529088
//   total ~51.4 MB

// ---------------- prep: BN scale/shift ----------------
__global__ void __launch_bounds__(1024) k_bnprep(
    const float* g1, const float* b1, const float* m1, const float* v1,
    const float* g2, const float* b2, const float* m2, const float* v2,
    const float* g3, const float* b3, const float* m3, const float* v3,
    float* bnc) {
    int t = threadIdx.x;
    if (t < 256) {
        float s = g1[t] * rsqrtf(v1[t] + BN_EPS);
        bnc[t] = s;
        bnc[256 + t] = b1[t] - m1[t] * s;
        float s2 = g2[t] * rsqrtf(v2[t] + BN_EPS);
        bnc[512 + t] = s2;
        bnc[768 + t] = b2[t] - m2[t] * s2;
    }
    float s3 = g3[t] * rsqrtf(v3[t] + BN_EPS);
    bnc[1024 + t] = s3;
    bnc[2048 + t] = b3[t] - m3[t] * s3;
}

// ---------------- prep: fp32 -> bf16 cast ----------------
__global__ void __launch_bounds__(256) k_cast(const float* __restrict__ s,
                                              bf16_t* __restrict__ d, int n4) {
    int i = blockIdx.x * 256 + threadIdx.x;
    if (i >= n4) return;
    float4 v = ((const float4*)s)[i];
    d[4 * i + 0] = (bf16_t)v.x;
    d[4 * i + 1] = (bf16_t)v.y;
    d[4 * i + 2] = (bf16_t)v.z;
    d[4 * i + 3] = (bf16_t)v.w;
}

// ---------------- prep: w2 (O,C,3,3) -> bf16 [o][k][c] ----------------
__global__ void __launch_bounds__(256) k_w2b(const float* __restrict__ w2,
                                             bf16_t* __restrict__ w2t) {
    int i = blockIdx.x * 256 + threadIdx.x; // out idx
    int o = i / 2304;
    int r = i - o * 2304;
    int kk = r >> 8;
    int c = r & 255;
    w2t[i] = (bf16_t)w2[(size_t)o * 2304 + c * 9 + kk];
}

// ---------------- prep: off_w (18,C,3,3) -> bf16 [j pad32][kp][c], 0-pad ----
__global__ void __launch_bounds__(256) k_owtb(const float* __restrict__ ow,
                                              bf16_t* __restrict__ owtb) {
    int idx = blockIdx.x * 256 + threadIdx.x; // 32*9*256 = 73728
    if (idx >= 73728) return;
    int j = idx / 2304;
    int rem = idx - j * 2304;
    int kp = rem >> 8;
    int c = rem & 255;
    float v = (j < 18) ? ow[(j * 256 + c) * 9 + kp] : 0.f;
    owtb[idx] = (bf16_t)v;
}

// ---------------- prep: x NCHW f32 -> xb NHWC bf16 ----------------
// grid (16 hw-tiles, 16 c-tiles, 16 b); 64c x 64hw tile via LDS
__global__ void __launch_bounds__(256) k_xb(const float* __restrict__ x,
                                            bf16_t* __restrict__ xb) {
    __shared__ float ld[64 * 68];
    int t = threadIdx.x;
    int hw0 = blockIdx.x * 64, c0 = blockIdx.y * 64, b = blockIdx.z;
    int ci = t >> 2, h0 = (t & 3) * 16;
    const float* src = x + ((size_t)(b * 1024 + c0 + ci) << 10) + hw0 + h0;
#pragma unroll
    for (int i = 0; i < 4; ++i)
        *(float4*)(ld + ci * 68 + h0 + 4 * i) = *(const float4*)(src + 4 * i);
    __syncthreads();
    int r = t >> 2, cc0 = (t & 3) * 16;
    bf16x8 o0, o1;
#pragma unroll
    for (int i = 0; i < 8; ++i) o0[i] = (bf16_t)ld[(cc0 + i) * 68 + r];
#pragma unroll
    for (int i = 0; i < 8; ++i) o1[i] = (bf16_t)ld[(cc0 + 8 + i) * 68 + r];
    bf16_t* dst = xb + ((size_t)(b * 1024 + hw0 + r) << 10) + c0 + cc0;
    *(bf16x8*)dst = o0;
    *(bf16x8*)(dst + 8) = o1;
}

// ---------------- shared MFMA GEMM: C[m][n] = A[m][K] * Bt[n][K]^T --------
// BM=64 BN=128 BK=32, 256 thr = 4 waves (2x2), wave: 32x64 (2x4 frags)
// epi 0: outb[m*ldo+n] = bf16(relu(acc*sc[n]+sh[n]))
// epi 1: outf NCHW fp32: relu(acc*sc[o]+sh[o] + resid), float4 rows
__global__ void __launch_bounds__(256) k_gemm64(
    const bf16_t* __restrict__ A, const bf16_t* __restrict__ Bt, int K, int ldo,
    const float* __restrict__ sc, const float* __restrict__ sh,
    const float* __restrict__ resid, bf16_t* __restrict__ outb,
    float* __restrict__ outf, int epi) {
    __shared__ __align__(16) bf16_t As[64 * 40];
    __shared__ __align__(16) bf16_t Bs[128 * 40];
    int t = threadIdx.x;
    int lane = t & 63;
    int w = t >> 6;
    int wm = w >> 1, wn = w & 1;
    int m0 = blockIdx.x * 64, n0 = blockIdx.y * 128;

    // staging maps
    int ar = t >> 2, as_ = t & 3;
    const bf16_t* ag = A + (size_t)(m0 + ar) * K + as_ * 8;
    int aw = ar * 40 + ((as_ ^ (ar & 3)) * 8);
    int bn0 = t >> 2, bs_ = t & 3;
    const bf16_t* bg0 = Bt + (size_t)(n0 + bn0) * K + bs_ * 8;
    const bf16_t* bg1 = Bt + (size_t)(n0 + 64 + bn0) * K + bs_ * 8;
    int bw0 = bn0 * 40 + ((bs_ ^ (bn0 & 3)) * 8);
    int bw1 = (64 + bn0) * 40 + ((bs_ ^ (bn0 & 3)) * 8);

    // fragment read offsets
    int asel = lane >> 4;
    int ar0 = wm * 32 + (lane & 15);
    int aoff0 = ar0 * 40 + ((asel ^ (ar0 & 3)) * 8);
    int aoff1 = (ar0 + 16) * 40 + ((asel ^ (ar0 & 3)) * 8);
    int boff[4];
#pragma unroll
    for (int ni = 0; ni < 4; ++ni) {
        int n = wn * 64 + ni * 16 + (lane & 15);
        boff[ni] = n * 40 + ((asel ^ (n & 3)) * 8);
    }
    f32x4 acc[2][4] = {};

    for (int k0 = 0; k0 < K; k0 += 32) {
        __syncthreads();
        *(bf16x8*)(As + aw) = *(const bf16x8*)(ag + k0);
        *(bf16x8*)(Bs + bw0) = *(const bf16x8*)(bg0 + k0);
        *(bf16x8*)(Bs + bw1) = *(const bf16x8*)(bg1 + k0);
        __syncthreads();
        bf16x8 a0 = *(const bf16x8*)(As + aoff0);
        bf16x8 a1 = *(const bf16x8*)(As + aoff1);
#pragma unroll
        for (int ni = 0; ni < 4; ++ni) {
            bf16x8 bv = *(const bf16x8*)(Bs + boff[ni]);
            acc[0][ni] = __builtin_amdgcn_mfma_f32_16x16x32_bf16(a0, bv, acc[0][ni], 0, 0, 0);
            acc[1][ni] = __builtin_amdgcn_mfma_f32_16x16x32_bf16(a1, bv, acc[1][ni], 0, 0, 0);
        }
    }

    int mrb = m0 + wm * 32 + (lane >> 4) * 4;
    int ncb = n0 + wn * 64 + (lane & 15);
    if (epi == 0) {
#pragma unroll
        for (int mi = 0; mi < 2; ++mi)
#pragma unroll
            for (int ni = 0; ni < 4; ++ni) {
                int n = ncb + ni * 16;
                float s = sc[n], h = sh[n];
#pragma unroll
                for (int j = 0; j < 4; ++j) {
                    int m = mrb + mi * 16 + j;
                    float v = fmaxf(fmaf(acc[mi][ni][j], s, h), 0.f);
                    outb[(size_t)m * ldo + n] = (bf16_t)v;
                }
            }
    } else {
#pragma unroll
        for (int mi = 0; mi < 2; ++mi) {
            int m = mrb + mi * 16;
            int bb = m >> 10, hw = m & 1023;
#pragma unroll
            for (int ni = 0; ni < 4; ++ni) {
                int o = ncb + ni * 16;
                float s = sc[o], h = sh[o];
                size_t idx = (((size_t)(bb * 1024 + o)) << 10) + hw;
                float4 r = *(const float4*)(resid + idx);
                float4 v;
                v.x = fmaxf(fmaf(acc[mi][ni][0], s, h) + r.x, 0.f);
                v.y = fmaxf(fmaf(acc[mi][ni][1], s, h) + r.y, 0.f);
                v.z = fmaxf(fmaf(acc[mi][ni][2], s, h) + r.z, 0.f);
                v.w = fmaxf(fmaf(acc[mi][ni][3], s, h) + r.w, 0.f);
                *(float4*)(outf + idx) = v;
            }
        }
    }
}

// ---------------- K2: 3x3 offset conv, MFMA, no LDS ----------------
// grid (32 y, 16 b), 256 thr = 4 waves; wave w -> (mi = x-half, ni = j-half)
// M=32 (x), N=32 (j, 18 real), K=2304 (9 taps x 256 c). A frags read direct
// from h1 (L2-hot) with boundary zero-masking; B frags from zero-padded owtb.
__global__ void __launch_bounds__(256) k_off(const bf16_t* __restrict__ h1,
                                             const bf16_t* __restrict__ owtb,
                                             const float* __restrict__ offb,
                                             float* __restrict__ off) {
    int t = threadIdx.x;
    int lane = t & 63;
    int w = t >> 6;
    int mi = w >> 1, ni = w & 1;
    int y = blockIdx.x, b = blockIdx.y;
    int x = (lane & 15) + mi * 16;
    int ksel = lane >> 4;
    int j = (lane & 15) + ni * 16;
    f32x4 acc = {};
    const bf16_t* h1base = h1 + ((size_t)b << 18);
    const bf16_t* brow = owtb + (size_t)j * 2304 + ksel * 8;

    for (int kp = 0; kp < 9; ++kp) {
        int yy = y + kp / 3 - 1;
        int xx = x + kp % 3 - 1;
        bool vy = (yy >= 0) && (yy < 32);
        bool vx = (xx >= 0) && (xx < 32);
        const bf16_t* arow = h1base + (((size_t)(yy * 32 + xx)) << 8) + ksel * 8;
        const bf16_t* bp = brow + kp * 256;
#pragma unroll
        for (int s = 0; s < 8; ++s) {
            bf16x8 av = {};
            if (vy && vx) av = *(const bf16x8*)(arow + s * 32);
            bf16x8 bv = *(const bf16x8*)(bp + s * 32);
            acc = __builtin_amdgcn_mfma_f32_16x16x32_bf16(av, bv, acc, 0, 0, 0);
        }
    }
    if (j < 18) {
        float bias = offb[j];
        size_t ob = (size_t)b * 18432 + (size_t)j * 1024 + y * 32 + mi * 16;
#pragma unroll
        for (int r = 0; r < 4; ++r) {
            off[ob + ksel * 4 + r] = acc[r] + bias;
        }
    }
}

// ---------------- K3: deformable conv, MFMA, 2 barriers/tap ----------------
// grid (32 y, 16 b), 256 thr = 4 waves (wave wn owns n-range wn*64..+64).
// Per tap k: build samp As (8 panels [32][40]+8pad, gemm64 XOR swizzle),
// barrier, then 8 unrolled K-chunks: A from LDS, B direct from w2t (L2-hot),
// 8 MFMA each -- no inner barriers. Barrier at loop top protects As reuse.
__global__ void __launch_bounds__(256) k_deform(const bf16_t* __restrict__ h1,
                                                const float* __restrict__ off,
                                                const bf16_t* __restrict__ w2t,
                                                const float* __restrict__ bnc,
                                                bf16_t* __restrict__ h2) {
    __shared__ __align__(16) bf16_t As[8 * 1288]; // 8 panels x ([32][40] + 8)
    int t = threadIdx.x;
    int lane = t & 63;
    int wn = t >> 6;
    int y = blockIdx.x, b = blockIdx.y;
    int sx = t >> 3, scg = t & 7; // sample-build: row, c-group of 32
    int asel = lane >> 4;
    int ar0 = lane & 15;
    // A read offsets within a panel (proven gemm64 map)
    int aoff0 = ar0 * 40 + ((asel ^ (ar0 & 3)) * 8);
    int aoff1 = (ar0 + 16) * 40 + ((asel ^ ((ar0 + 16) & 3)) * 8);
    // B direct-global row pointers (L2-hot w2t, [o][kp][c])
    const bf16_t* br[4];
#pragma unroll
    for (int ni = 0; ni < 4; ++ni) {
        int n = wn * 64 + ni * 16 + (lane & 15);
        br[ni] = w2t + (size_t)n * 2304 + asel * 8;
    }
    f32x4 acc[2][4] = {};
    size_t obase = (size_t)b * 18432 + (size_t)y * 32 + sx;
    size_t h1row = (size_t)b * 1024;

    for (int k = 0; k < 9; ++k) {
        __syncthreads(); // previous tap's readers done with As
        // ---- build bilinear-sampled tile (bf16) into panels ----
        float oy = off[obase + (size_t)(2 * k) * 1024];
        float ox = off[obase + (size_t)(2 * k + 1) * 1024];
        float py = (float)y + (float)(k / 3 - 1) + oy;
        float px = (float)sx + (float)(k % 3 - 1) + ox;
        float fy = floorf(py), fx = floorf(px);
        float wy = py - fy, wx = px - fx;
        int y0 = (int)fy, x0 = (int)fx;
        int y1 = y0 + 1, x1 = x0 + 1;
        float vy0 = (y0 >= 0 && y0 < 32) ? 1.f : 0.f;
        float vy1 = (y1 >= 0 && y1 < 32) ? 1.f : 0.f;
        float vx0 = (x0 >= 0 && x0 < 32) ? 1.f : 0.f;
        float vx1 = (x1 >= 0 && x1 < 32) ? 1.f : 0.f;
        int yc0 = min(max(y0, 0), 31), yc1 = min(max(y1, 0), 31);
        int xc0 = min(max(x0, 0), 31), xc1 = min(max(x1, 0), 31);
        float w00 = (1.f - wy) * (1.f - wx) * vy0 * vx0;
        float w01 = (1.f - wy) * wx * vy0 * vx1;
        float w10 = wy * (1.f - wx) * vy1 * vx0;
        float w11 = wy * wx * vy1 * vx1;
        const bf16_t* p00 = h1 + ((h1row + yc0 * 32 + xc0) << 8);
        const bf16_t* p01 = h1 + ((h1row + yc0 * 32 + xc1) << 8);
        const bf16_t* p10 = h1 + ((h1row + yc1 * 32 + xc0) << 8);
        const bf16_t* p11 = h1 + ((h1row + yc1 * 32 + xc1) << 8);
        bf16_t* pnl = As + scg * 1288 + sx * 40;
#pragma unroll
        for (int q = 0; q < 4; ++q) {
            int c = scg * 32 + q * 8;
            bf16x8 v00 = *(const bf16x8*)(p00 + c);
            bf16x8 v01 = *(const bf16x8*)(p01 + c);
            bf16x8 v10 = *(const bf16x8*)(p10 + c);
            bf16x8 v11 = *(const bf16x8*)(p11 + c);
            bf16x8 r;
#pragma unroll
            for (int e = 0; e < 8; ++e) {
                float f = w00 * (float)v00[e] + w01 * (float)v01[e] +
                          w10 * (float)v10[e] + w11 * (float)v11[e];
                r[e] = (bf16_t)f;
            }
            *(bf16x8*)(pnl + ((q ^ (sx & 3)) * 8)) = r;
        }
        __syncthreads(); // As ready for all waves
        // ---- GEMM over c: 8 chunks of 32, no barriers ----
        const bf16_t* wb = w2t ? (const bf16_t*)0 : (const bf16_t*)0; (void)wb;
#pragma unroll
        for (int p = 0; p < 8; ++p) {
            const bf16_t* pb = As + p * 1288;
            bf16x8 a0 = *(const bf16x8*)(pb + aoff0);
            bf16x8 a1 = *(const bf16x8*)(pb + aoff1);
            int ko = k * 256 + p * 32;
#pragma unroll
            for (int ni = 0; ni < 4; ++ni) {
                bf16x8 bv = *(const bf16x8*)(br[ni] + ko);
                acc[0][ni] = __builtin_amdgcn_mfma_f32_16x16x32_bf16(a0, bv, acc[0][ni], 0, 0, 0);
                acc[1][ni] = __builtin_amdgcn_mfma_f32_16x16x32_bf16(a1, bv, acc[1][ni], 0, 0, 0);
            }
        }
    }
    // epilogue: BN2 + ReLU -> h2 bf16
    int mrb = (lane >> 4) * 4;
    int ncb = wn * 64 + (lane & 15);
#pragma unroll
    for (int mi = 0; mi < 2; ++mi)
#pragma unroll
        for (int ni = 0; ni < 4; ++ni) {
            int n = ncb + ni * 16;
            float s = bnc[512 + n], h = bnc[768 + n];
#pragma unroll
            for (int j = 0; j < 4; ++j) {
                int row = mrb + mi * 16 + j;
                float v = fmaxf(fmaf(acc[mi][ni][j], s, h), 0.f);
                h2[(((size_t)(b * 1024 + y * 32 + row)) << 8) + n] = (bf16_t)v;
            }
        }
}

extern "C" void kernel_launch(void* const* d_in, const int* in_sizes, int n_in,
                              void* d_out, int out_size, void* d_ws, size_t ws_size,
                              hipStream_t stream) {
    const float* x = (const float*)d_in[0];
    const float* w1 = (const float*)d_in[1];
    const float* bn1g = (const float*)d_in[2];
    const float* bn1b = (const float*)d_in[3];
    const float* bn1m = (const float*)d_in[4];
    const float* bn1v = (const float*)d_in[5];
    const float* off_w = (const float*)d_in[6];
    const float* off_b = (const float*)d_in[7];
    const float* w2 = (const float*)d_in[8];
    const float* bn2g = (const float*)d_in[9];
    const float* bn2b = (const float*)d_in[10];
    const float* bn2m = (const float*)d_in[11];
    const float* bn2v = (const float*)d_in[12];
    const float* w3 = (const float*)d_in[13];
    const float* bn3g = (const float*)d_in[14];
    const float* bn3b = (const float*)d_in[15];
    const float* bn3m = (const float*)d_in[16];
    const float* bn3v = (const float*)d_in[17];
    float* out = (float*)d_out;

    char* ws = (char*)d_ws;
    float* bnc = (float*)(ws + 0);
    bf16_t* owtb = (bf16_t*)(ws + 12288);
    float* off = (float*)(ws + 178176);
    bf16_t* xb = (bf16_t*)(ws + 1357824);
    bf16_t* w1b = (bf16_t*)(ws + 34912256);
    bf16_t* w2tb = (bf16_t*)(ws + 35436544);
    bf16_t* w3b = (bf16_t*)(ws + 36616192);
    bf16_t* h1b = (bf16_t*)(ws + 37140480);
    bf16_t* h2b = (bf16_t*)(ws + 45529088);

    k_bnprep<<<1, 1024, 0, stream>>>(bn1g, bn1b, bn1m, bn1v, bn2g, bn2b, bn2m,
                                     bn2v, bn3g, bn3b, bn3m, bn3v, bnc);
    k_cast<<<256, 256, 0, stream>>>(w1, w1b, 65536);
    k_cast<<<256, 256, 0, stream>>>(w3, w3b, 65536);
    k_w2b<<<2304, 256, 0, stream>>>(w2, w2tb);
    k_owtb<<<288, 256, 0, stream>>>(off_w, owtb);
    k_xb<<<dim3(16, 16, 16), 256, 0, stream>>>(x, xb);
    // conv1: M=16384 N=256 K=1024
    k_gemm64<<<dim3(256, 2), 256, 0, stream>>>(xb, w1b, 1024, 256, bnc,
                                               bnc + 256, nullptr, h1b, nullptr, 0);
    k_off<<<dim3(32, 16), 256, 0, stream>>>(h1b, owtb, off_b, off);
    k_deform<<<dim3(32, 16), 256, 0, stream>>>(h1b, off, w2tb, bnc, h2b);
    // conv3: M=16384 N=1024 K=256, residual + BN3 + ReLU -> out NCHW f32
    k_gemm64<<<dim3(256, 8), 256, 0, stream>>>(h2b, w3b, 256, 1024, bnc + 1024,
                                               bnc + 2048, x, nullptr, out, 1);
}